// Round 2
// baseline (1822.985 us; speedup 1.0000x reference)
//
#include <hip/hip_runtime.h>

namespace {

constexpr int B = 4;
constexpr int N = 2048;
constexpr int E = 1024;
constexpr int H = 16;
constexpr int D = 64;
constexpr int M = B * N;          // 8192
constexpr float SCALE = 0.125f;   // 1/sqrt(D)
constexpr int LP = 68;            // attn LDS pad (floats)

typedef __attribute__((ext_vector_type(8))) short bf16x8;
typedef __attribute__((ext_vector_type(4))) float f32x4;

__device__ inline ushort bf16_rne(float f) {
  unsigned u = __float_as_uint(f);
  return (ushort)((u + 0x7FFFu + ((u >> 16) & 1u)) >> 16);
}
// fp32 -> hi (truncated bf16) + lo (rne bf16 of remainder); hi+lo ~ 17-bit mantissa
__device__ inline void split2(float f, ushort& hi, ushort& lo) {
  unsigned u = __float_as_uint(f);
  hi = (ushort)(u >> 16);
  lo = bf16_rne(f - __uint_as_float(u & 0xFFFF0000u));
}

// ---------------------------------------------------------------------------
// Elementwise fp32 -> (hi, lo) bf16 split
// ---------------------------------------------------------------------------
__global__ __launch_bounds__(256) void split_kernel(
    const float* __restrict__ in, ushort* __restrict__ hi,
    ushort* __restrict__ lo, int n4) {
  int i = blockIdx.x * blockDim.x + threadIdx.x;
  const int stride = gridDim.x * blockDim.x;
  for (; i < n4; i += stride) {
    const float4 f = ((const float4*)in)[i];
    ushort4 h, l;
    split2(f.x, h.x, l.x);
    split2(f.y, h.y, l.y);
    split2(f.z, h.z, l.z);
    split2(f.w, h.w, l.w);
    ((ushort4*)hi)[i] = h;
    ((ushort4*)lo)[i] = l;
  }
}

// ---------------------------------------------------------------------------
// bf16x3 MFMA GEMM: C[m][n] = sum_k A[m][k]*B[n][k] (+bias), fp32-accurate via
// Ah*Bh + Ah*Bl + Al*Bh.  Tile 128x128, BK=32, 256 thr = 4 waves (2x2), each
// wave 64x64 = 4x4 blocks of mfma_f32_16x16x32_bf16.
// LDS tiles are linear [128][32] bf16 (64B rows), staged by global_load_lds.
// MODE 0: epilogue scatters QKV (col = h*192 + d*3 + s) into Q/K/V [B,H,N,D].
// MODE 1: epilogue writes out[m][col] + bias.
// ---------------------------------------------------------------------------
template <int MODE>
__global__ __launch_bounds__(256) void gemm_x3(
    const ushort* __restrict__ Ahg, const ushort* __restrict__ Alg,
    const ushort* __restrict__ Bhg, const ushort* __restrict__ Blg,
    const float* __restrict__ bias, float* __restrict__ Qb,
    float* __restrict__ Kb, float* __restrict__ Vb, float* __restrict__ outp) {
  __shared__ ushort LAh[4096], LAl[4096], LBh[4096], LBl[4096];
  const int tid = threadIdx.x;
  const int l = tid & 63, wid = tid >> 6;
  const int wr = wid >> 1, wc = wid & 1;
  const int lr = l & 15, kg = l >> 4;
  const int m0 = blockIdx.x * 128, n0 = blockIdx.y * 128;

  f32x4 acc[4][4];
#pragma unroll
  for (int i = 0; i < 4; ++i)
#pragma unroll
    for (int j = 0; j < 4; ++j) acc[i][j] = (f32x4){0.f, 0.f, 0.f, 0.f};

  for (int k0 = 0; k0 < E; k0 += 32) {
    const ushort* gAh = Ahg + (size_t)m0 * E + k0;
    const ushort* gAl = Alg + (size_t)m0 * E + k0;
    const ushort* gBh = Bhg + (size_t)n0 * E + k0;
    const ushort* gBl = Blg + (size_t)n0 * E + k0;
    __syncthreads();  // all waves done reading previous tile
    // Stage 4 tiles x 8KB via global_load_lds(16B). chunk c in [0,512):
    // row = c>>2, k-offset = (c&3)*8 bf16. LDS dst is wave-uniform base,
    // lanes land at base + lane*16 (linear layout required).
    auto stage = [&](const ushort* gp, ushort* lp, int half) {
      const int c = half * 256 + tid;
      __builtin_amdgcn_global_load_lds(
          (__attribute__((address_space(1))) void*)(gp + (size_t)(c >> 2) * E +
                                                    (c & 3) * 8),
          (__attribute__((address_space(3))) void*)(lp +
                                                    (half * 256 + (tid & ~63)) * 8),
          16, 0, 0);
    };
    stage(gAh, LAh, 0); stage(gAh, LAh, 1);
    stage(gAl, LAl, 0); stage(gAl, LAl, 1);
    stage(gBh, LBh, 0); stage(gBh, LBh, 1);
    stage(gBl, LBl, 0); stage(gBl, LBl, 1);
    __syncthreads();  // drains vmcnt(0): tiles landed

    bf16x8 aH[4], aL[4], bH[4], bL[4];
#pragma unroll
    for (int rb = 0; rb < 4; ++rb) {
      const int off = (wr * 64 + rb * 16 + lr) * 32 + kg * 8;
      aH[rb] = *(const bf16x8*)(LAh + off);
      aL[rb] = *(const bf16x8*)(LAl + off);
    }
#pragma unroll
    for (int cb = 0; cb < 4; ++cb) {
      const int off = (wc * 64 + cb * 16 + lr) * 32 + kg * 8;
      bH[cb] = *(const bf16x8*)(LBh + off);
      bL[cb] = *(const bf16x8*)(LBl + off);
    }
#pragma unroll
    for (int rb = 0; rb < 4; ++rb)
#pragma unroll
      for (int cb = 0; cb < 4; ++cb) {
        acc[rb][cb] = __builtin_amdgcn_mfma_f32_16x16x32_bf16(
            aH[rb], bH[cb], acc[rb][cb], 0, 0, 0);
        acc[rb][cb] = __builtin_amdgcn_mfma_f32_16x16x32_bf16(
            aH[rb], bL[cb], acc[rb][cb], 0, 0, 0);
        acc[rb][cb] = __builtin_amdgcn_mfma_f32_16x16x32_bf16(
            aL[rb], bH[cb], acc[rb][cb], 0, 0, 0);
      }
  }

  // Epilogue. C/D layout (m89-verified): col = lane&15, row = (lane>>4)*4+reg.
#pragma unroll
  for (int cb = 0; cb < 4; ++cb) {
    const int col = n0 + wc * 64 + cb * 16 + lr;
    const float bv = bias[col];
    if (MODE == 0) {
      const int h = col / 192;
      const int rem = col - h * 192;
      const int dd = rem / 3;
      const int s = rem - dd * 3;
#pragma unroll
      for (int rb = 0; rb < 4; ++rb)
#pragma unroll
        for (int r = 0; r < 4; ++r) {
          const int m = m0 + wr * 64 + rb * 16 + kg * 4 + r;
          const int bb = m >> 11, nn = m & (N - 1);
          const size_t idx = (((size_t)bb * H + h) * N + nn) * D + dd;
          const float v = acc[rb][cb][r] + bv;
          if (s == 0) Qb[idx] = v;
          else if (s == 1) Kb[idx] = v;
          else Vb[idx] = v;
        }
    } else {
#pragma unroll
      for (int rb = 0; rb < 4; ++rb)
#pragma unroll
        for (int r = 0; r < 4; ++r) {
          const int m = m0 + wr * 64 + rb * 16 + kg * 4 + r;
          outp[(size_t)m * E + col] = acc[rb][cb][r] + bv;
        }
    }
  }
}

// ---------------------------------------------------------------------------
// Flash attention (fp32 VALU, round-0 structure). Epilogue now emits the
// proj-GEMM input as (hi, lo) bf16 split in [b, n, h*D+d] layout.
// ---------------------------------------------------------------------------
__global__ __launch_bounds__(256) void attn_kernel(
    const float* __restrict__ Qb, const float* __restrict__ Kb,
    const float* __restrict__ Vb, ushort* __restrict__ Aoh,
    ushort* __restrict__ Aol) {
  __shared__ float Qs[D][LP];    // [d][r]
  __shared__ float Ks[D][LP];    // [d][c]
  __shared__ float Vs[64][LP];   // [k][c]
  __shared__ float Ps[64][LP];   // [k][r]

  const int tid = threadIdx.x;
  const int tx = tid & 15;
  const int ty = tid >> 4;
  const int bh = blockIdx.y;
  const int bb = bh >> 4;
  const int hh = bh & 15;
  const int q0 = blockIdx.x * 64;

  const float* Qp = Qb + ((size_t)bh * N + q0) * D;
  const float* Kp = Kb + (size_t)bh * N * D;
  const float* Vp = Vb + (size_t)bh * N * D;

#pragma unroll
  for (int it = 0; it < 4; ++it) {
    const int f = tid + 256 * it;
    const int r = f >> 4;
    const int c4 = (f & 15) * 4;
    const float4 q = *(const float4*)(Qp + (size_t)r * D + c4);
    Qs[c4 + 0][r] = q.x; Qs[c4 + 1][r] = q.y;
    Qs[c4 + 2][r] = q.z; Qs[c4 + 3][r] = q.w;
  }

  float m_run[4], l_run[4], o[4][4];
#pragma unroll
  for (int i = 0; i < 4; ++i) {
    m_run[i] = -1e30f;
    l_run[i] = 0.f;
#pragma unroll
    for (int j = 0; j < 4; ++j) o[i][j] = 0.f;
  }

  for (int kt = 0; kt < N / 64; ++kt) {
    const float* Kt = Kp + (size_t)kt * 64 * D;
    const float* Vt = Vp + (size_t)kt * 64 * D;
    __syncthreads();
#pragma unroll
    for (int it = 0; it < 4; ++it) {
      const int f = tid + 256 * it;
      const int r = f >> 4;
      const int c4 = (f & 15) * 4;
      const float4 kv = *(const float4*)(Kt + (size_t)r * D + c4);
      Ks[c4 + 0][r] = kv.x; Ks[c4 + 1][r] = kv.y;
      Ks[c4 + 2][r] = kv.z; Ks[c4 + 3][r] = kv.w;
      *(float4*)(&Vs[r][c4]) = *(const float4*)(Vt + (size_t)r * D + c4);
    }
    __syncthreads();

    float s[4][4] = {};
#pragma unroll
    for (int d = 0; d < D; ++d) {
      const float4 qv = *(const float4*)(&Qs[d][ty * 4]);
      const float4 kv = *(const float4*)(&Ks[d][tx * 4]);
      const float qr[4] = {qv.x, qv.y, qv.z, qv.w};
      const float kr[4] = {kv.x, kv.y, kv.z, kv.w};
#pragma unroll
      for (int i = 0; i < 4; ++i)
#pragma unroll
        for (int j = 0; j < 4; ++j) s[i][j] = fmaf(qr[i], kr[j], s[i][j]);
    }

#pragma unroll
    for (int i = 0; i < 4; ++i) {
#pragma unroll
      for (int j = 0; j < 4; ++j) s[i][j] *= SCALE;
      float mx = fmaxf(fmaxf(s[i][0], s[i][1]), fmaxf(s[i][2], s[i][3]));
#pragma unroll
      for (int off = 8; off; off >>= 1) mx = fmaxf(mx, __shfl_xor(mx, off, 16));
      const float mnew = fmaxf(m_run[i], mx);
      const float fac = __expf(m_run[i] - mnew);
      m_run[i] = mnew;
      float ps = 0.f;
#pragma unroll
      for (int j = 0; j < 4; ++j) {
        s[i][j] = __expf(s[i][j] - mnew);
        ps += s[i][j];
      }
#pragma unroll
      for (int off = 8; off; off >>= 1) ps += __shfl_xor(ps, off, 16);
      l_run[i] = l_run[i] * fac + ps;
#pragma unroll
      for (int j = 0; j < 4; ++j) o[i][j] *= fac;
    }

#pragma unroll
    for (int i = 0; i < 4; ++i)
#pragma unroll
      for (int j = 0; j < 4; ++j) Ps[tx * 4 + j][ty * 4 + i] = s[i][j];
    __syncthreads();

#pragma unroll
    for (int k = 0; k < 64; ++k) {
      const float4 pv = *(const float4*)(&Ps[k][ty * 4]);
      const float4 vv = *(const float4*)(&Vs[k][tx * 4]);
      const float pr[4] = {pv.x, pv.y, pv.z, pv.w};
      const float vr[4] = {vv.x, vv.y, vv.z, vv.w};
#pragma unroll
      for (int i = 0; i < 4; ++i)
#pragma unroll
        for (int j = 0; j < 4; ++j) o[i][j] = fmaf(pr[i], vr[j], o[i][j]);
    }
  }

#pragma unroll
  for (int i = 0; i < 4; ++i) {
    const float inv = 1.f / l_run[i];
    const int n = q0 + ty * 4 + i;
    ushort4 hv, lv;
    split2(o[i][0] * inv, hv.x, lv.x);
    split2(o[i][1] * inv, hv.y, lv.y);
    split2(o[i][2] * inv, hv.z, lv.z);
    split2(o[i][3] * inv, hv.w, lv.w);
    const size_t base = ((size_t)bb * N + n) * E + hh * D + tx * 4;
    *(ushort4*)(Aoh + base) = hv;
    *(ushort4*)(Aol + base) = lv;
  }
}

}  // namespace

extern "C" void kernel_launch(void* const* d_in, const int* in_sizes, int n_in,
                              void* d_out, int out_size, void* d_ws,
                              size_t ws_size, hipStream_t stream) {
  (void)in_sizes; (void)n_in; (void)out_size; (void)ws_size;
  const float* x      = (const float*)d_in[0];
  const float* w_qkv  = (const float*)d_in[1];
  const float* b_qkv  = (const float*)d_in[2];
  const float* w_proj = (const float*)d_in[3];
  const float* b_proj = (const float*)d_in[4];
  float* out = (float*)d_out;

  constexpr size_t MB = 1ull << 20;
  char* w = (char*)d_ws;
  float*  Qb  = (float*)(w + 0 * MB);     // 32 MB
  float*  Kb  = (float*)(w + 32 * MB);    // 32 MB
  float*  Vb  = (float*)(w + 64 * MB);    // 32 MB
  ushort* xh  = (ushort*)(w + 96 * MB);   // 16 MB
  ushort* xl  = (ushort*)(w + 112 * MB);  // 16 MB
  ushort* wqh = (ushort*)(w + 128 * MB);  // 6 MB
  ushort* wql = (ushort*)(w + 134 * MB);  // 6 MB
  ushort* wph = (ushort*)(w + 140 * MB);  // 2 MB
  ushort* wpl = (ushort*)(w + 142 * MB);  // 2 MB
  ushort* Aoh = (ushort*)(w + 144 * MB);  // 16 MB
  ushort* Aol = (ushort*)(w + 160 * MB);  // 16 MB  (total 176 MB)

  split_kernel<<<2048, 256, 0, stream>>>(x, xh, xl, (M * E) / 4);
  split_kernel<<<1024, 256, 0, stream>>>(w_qkv, wqh, wql, (3 * E * E) / 4);
  split_kernel<<<512, 256, 0, stream>>>(w_proj, wph, wpl, (E * E) / 4);

  gemm_x3<0><<<dim3(M / 128, 3 * E / 128), 256, 0, stream>>>(
      xh, xl, wqh, wql, b_qkv, Qb, Kb, Vb, nullptr);

  attn_kernel<<<dim3(N / 64, B * H), 256, 0, stream>>>(Qb, Kb, Vb, Aoh, Aol);

  gemm_x3<1><<<dim3(M / 128, E / 128), 256, 0, stream>>>(
      Aoh, Aol, wph, wpl, b_proj, nullptr, nullptr, nullptr, out);
}

// Round 4
// 1127.918 us; speedup vs baseline: 1.6162x; 1.6162x over previous
//
#include <hip/hip_runtime.h>
#include <hip/hip_fp16.h>

namespace {

constexpr int B = 4;
constexpr int N = 2048;
constexpr int E = 1024;
constexpr int H = 16;
constexpr int D = 64;
constexpr int M = B * N;  // 8192

typedef __attribute__((ext_vector_type(8))) short bf16x8;
typedef __attribute__((ext_vector_type(8))) _Float16 f16x8;
typedef __attribute__((ext_vector_type(4))) float f32x4;

__device__ inline ushort bf16_rne(float f) {
  unsigned u = __float_as_uint(f);
  return (ushort)((u + 0x7FFFu + ((u >> 16) & 1u)) >> 16);
}
// fp32 -> hi (truncated bf16) + lo (rne bf16 of remainder); hi+lo ~ 17-bit mantissa
__device__ inline void split2(float f, ushort& hi, ushort& lo) {
  unsigned u = __float_as_uint(f);
  hi = (ushort)(u >> 16);
  lo = bf16_rne(f - __uint_as_float(u & 0xFFFF0000u));
}

// ---------------------------------------------------------------------------
// Elementwise fp32 -> (hi, lo) bf16 split
// ---------------------------------------------------------------------------
__global__ __launch_bounds__(256) void split_kernel(
    const float* __restrict__ in, ushort* __restrict__ hi,
    ushort* __restrict__ lo, int n4) {
  int i = blockIdx.x * blockDim.x + threadIdx.x;
  const int stride = gridDim.x * blockDim.x;
  for (; i < n4; i += stride) {
    const float4 f = ((const float4*)in)[i];
    ushort4 h, l;
    split2(f.x, h.x, l.x);
    split2(f.y, h.y, l.y);
    split2(f.z, h.z, l.z);
    split2(f.w, h.w, l.w);
    ((ushort4*)hi)[i] = h;
    ((ushort4*)lo)[i] = l;
  }
}

// ---------------------------------------------------------------------------
// bf16x3 MFMA GEMM (validated round 2). Tile 128x128, BK=32, 4 waves.
// MODE 0 epilogue: col = h*192 + d*3 + s ->
//   s==0: Q *(1/8) split -> Qh/Ql  [B,H,N,D] bf16
//   s==1: K split        -> Kh/Kl  [B,H,N,D] bf16
//   s==2: V              -> Vt     [B,H,D,N] fp16 (transposed)
// MODE 1 epilogue: out[m][col] = acc + bias (fp32)
// ---------------------------------------------------------------------------
template <int MODE>
__global__ __launch_bounds__(256) void gemm_x3(
    const ushort* __restrict__ Ahg, const ushort* __restrict__ Alg,
    const ushort* __restrict__ Bhg, const ushort* __restrict__ Blg,
    const float* __restrict__ bias, ushort* __restrict__ qh,
    ushort* __restrict__ ql, ushort* __restrict__ kh, ushort* __restrict__ kl,
    ushort* __restrict__ vt, float* __restrict__ outp) {
  __shared__ ushort LAh[4096], LAl[4096], LBh[4096], LBl[4096];
  const int tid = threadIdx.x;
  const int l = tid & 63, wid = tid >> 6;
  const int wr = wid >> 1, wc = wid & 1;
  const int lr = l & 15, kg = l >> 4;
  const int m0 = blockIdx.x * 128, n0 = blockIdx.y * 128;

  f32x4 acc[4][4];
#pragma unroll
  for (int i = 0; i < 4; ++i)
#pragma unroll
    for (int j = 0; j < 4; ++j) acc[i][j] = (f32x4){0.f, 0.f, 0.f, 0.f};

  for (int k0 = 0; k0 < E; k0 += 32) {
    const ushort* gAh = Ahg + (size_t)m0 * E + k0;
    const ushort* gAl = Alg + (size_t)m0 * E + k0;
    const ushort* gBh = Bhg + (size_t)n0 * E + k0;
    const ushort* gBl = Blg + (size_t)n0 * E + k0;
    __syncthreads();
    auto stage = [&](const ushort* gp, ushort* lp, int half) {
      const int c = half * 256 + tid;
      __builtin_amdgcn_global_load_lds(
          (__attribute__((address_space(1))) void*)(gp + (size_t)(c >> 2) * E +
                                                    (c & 3) * 8),
          (__attribute__((address_space(3))) void*)(lp +
                                                    (half * 256 + (tid & ~63)) * 8),
          16, 0, 0);
    };
    stage(gAh, LAh, 0); stage(gAh, LAh, 1);
    stage(gAl, LAl, 0); stage(gAl, LAl, 1);
    stage(gBh, LBh, 0); stage(gBh, LBh, 1);
    stage(gBl, LBl, 0); stage(gBl, LBl, 1);
    __syncthreads();

    bf16x8 aH[4], aL[4], bH[4], bL[4];
#pragma unroll
    for (int rb = 0; rb < 4; ++rb) {
      const int off = (wr * 64 + rb * 16 + lr) * 32 + kg * 8;
      aH[rb] = *(const bf16x8*)(LAh + off);
      aL[rb] = *(const bf16x8*)(LAl + off);
    }
#pragma unroll
    for (int cb = 0; cb < 4; ++cb) {
      const int off = (wc * 64 + cb * 16 + lr) * 32 + kg * 8;
      bH[cb] = *(const bf16x8*)(LBh + off);
      bL[cb] = *(const bf16x8*)(LBl + off);
    }
#pragma unroll
    for (int rb = 0; rb < 4; ++rb)
#pragma unroll
      for (int cb = 0; cb < 4; ++cb) {
        acc[rb][cb] = __builtin_amdgcn_mfma_f32_16x16x32_bf16(
            aH[rb], bH[cb], acc[rb][cb], 0, 0, 0);
        acc[rb][cb] = __builtin_amdgcn_mfma_f32_16x16x32_bf16(
            aH[rb], bL[cb], acc[rb][cb], 0, 0, 0);
        acc[rb][cb] = __builtin_amdgcn_mfma_f32_16x16x32_bf16(
            aL[rb], bH[cb], acc[rb][cb], 0, 0, 0);
      }
  }

  // C/D layout: col = lane&15, row = (lane>>4)*4 + reg.
#pragma unroll
  for (int cb = 0; cb < 4; ++cb) {
    const int col = n0 + wc * 64 + cb * 16 + lr;
    const float bv = bias[col];
    if (MODE == 0) {
      const int h = col / 192;
      const int rem = col - h * 192;
      const int dd = rem / 3;
      const int s = rem - dd * 3;
#pragma unroll
      for (int rb = 0; rb < 4; ++rb)
#pragma unroll
        for (int r = 0; r < 4; ++r) {
          const int m = m0 + wr * 64 + rb * 16 + kg * 4 + r;
          const int bb = m >> 11, nn = m & (N - 1);
          float v = acc[rb][cb][r] + bv;
          if (s == 0) {
            v *= 0.125f;  // fold 1/sqrt(D), exact pow2
            ushort hi, lo;
            split2(v, hi, lo);
            const size_t idx = (((size_t)bb * H + h) * N + nn) * D + dd;
            qh[idx] = hi; ql[idx] = lo;
          } else if (s == 1) {
            ushort hi, lo;
            split2(v, hi, lo);
            const size_t idx = (((size_t)bb * H + h) * N + nn) * D + dd;
            kh[idx] = hi; kl[idx] = lo;
          } else {
            ((_Float16*)vt)[(((size_t)bb * H + h) * D + dd) * N + nn] =
                (_Float16)v;
          }
        }
    } else {
#pragma unroll
      for (int rb = 0; rb < 4; ++rb)
#pragma unroll
        for (int r = 0; r < 4; ++r) {
          const int m = m0 + wr * 64 + rb * 16 + kg * 4 + r;
          outp[(size_t)m * E + col] = acc[rb][cb][r] + bv;
        }
    }
  }
}

// ---------------------------------------------------------------------------
// MFMA flash attention. Grid (B*H, N/256); block = 4 waves, each owning 64
// Q-rows. KVBLK = 64. QK^T: bf16x3 (Qh*Kh + Qh*Kl + Ql*Kh). PV: fp16.
// K/V LDS tiles are [64][64] elem (128 B rows) with byte^=(row&7)<<4 swizzle;
// staged by global_load_lds with pre-swizzled global source (linear LDS dst).
// P goes through a per-wave swizzled fp16 LDS buffer (C-layout -> A-layout).
// Output written as (hi,lo) bf16 split in [B, N, E] layout for proj GEMM.
// ---------------------------------------------------------------------------
__global__ __launch_bounds__(256, 2) void attn_mfma(
    const ushort* __restrict__ Qh, const ushort* __restrict__ Ql,
    const ushort* __restrict__ Kh, const ushort* __restrict__ Kl,
    const ushort* __restrict__ Vt, ushort* __restrict__ Aoh,
    ushort* __restrict__ Aol) {
  __shared__ ushort KhL[4096], KlL[4096], VtL[4096], PsL[4][4096];
  const int tid = threadIdx.x;
  const int l = tid & 63, w = tid >> 6;
  const int lr = l & 15, g = l >> 4;
  const int bh = blockIdx.x, bb = bh >> 4, hh = bh & 15;
  const int q0 = blockIdx.y * 256 + w * 64;

  // Q A-fragments (scale pre-folded): row = lane&15, k = (lane>>4)*8 + e
  bf16x8 qfh[4][2], qfl[4][2];
#pragma unroll
  for (int rb = 0; rb < 4; ++rb)
#pragma unroll
    for (int ks = 0; ks < 2; ++ks) {
      const size_t off =
          ((size_t)bh * N + q0 + rb * 16 + lr) * D + ks * 32 + g * 8;
      qfh[rb][ks] = *(const bf16x8*)(Qh + off);
      qfl[rb][ks] = *(const bf16x8*)(Ql + off);
    }

  f32x4 o[4][4];
  float m_[4][4], l_[4][4];
#pragma unroll
  for (int rb = 0; rb < 4; ++rb)
#pragma unroll
    for (int r = 0; r < 4; ++r) {
      m_[rb][r] = -1e30f;
      l_[rb][r] = 0.f;
      o[rb][r] = (f32x4){0.f, 0.f, 0.f, 0.f};
    }

  ushort* Pw = &PsL[w][0];

  for (int kt = 0; kt < N / 64; ++kt) {
    __syncthreads();  // prev iteration's K/V reads complete
    // Stage K hi/lo + Vt: 64x64 elem tiles, swizzled via pre-swizzled source.
#pragma unroll
    for (int bch = 0; bch < 2; ++bch) {
      const int s = bch * 256 + tid;
      const int r = s >> 3, c = s & 7;
      const int cc = (c ^ (r & 7)) * 8;
      const int dst = (bch * 256 + (tid & ~63)) * 8;
      const size_t ko = ((size_t)bh * N + kt * 64 + r) * D + cc;
      const size_t vo = ((size_t)bh * D + r) * N + kt * 64 + cc;
      __builtin_amdgcn_global_load_lds(
          (__attribute__((address_space(1))) void*)(Kh + ko),
          (__attribute__((address_space(3))) void*)(KhL + dst), 16, 0, 0);
      __builtin_amdgcn_global_load_lds(
          (__attribute__((address_space(1))) void*)(Kl + ko),
          (__attribute__((address_space(3))) void*)(KlL + dst), 16, 0, 0);
      __builtin_amdgcn_global_load_lds(
          (__attribute__((address_space(1))) void*)(Vt + vo),
          (__attribute__((address_space(3))) void*)(VtL + dst), 16, 0, 0);
    }
    __syncthreads();  // tiles landed (vmcnt drained by barrier)

    // S = Q K^T (x3). B-frag: row = cb*16+lr, chunk = (ks*4+g) ^ (lr&7).
    f32x4 s4[4][4];
#pragma unroll
    for (int rb = 0; rb < 4; ++rb)
#pragma unroll
      for (int cb = 0; cb < 4; ++cb) s4[rb][cb] = (f32x4){0.f, 0.f, 0.f, 0.f};
#pragma unroll
    for (int ks = 0; ks < 2; ++ks) {
      bf16x8 kfh[4], kfl[4];
#pragma unroll
      for (int cb = 0; cb < 4; ++cb) {
        const int sl = (cb * 16 + lr) * 8 + ((ks * 4 + g) ^ (lr & 7));
        kfh[cb] = *(const bf16x8*)(KhL + sl * 8);
        kfl[cb] = *(const bf16x8*)(KlL + sl * 8);
      }
#pragma unroll
      for (int rb = 0; rb < 4; ++rb)
#pragma unroll
        for (int cb = 0; cb < 4; ++cb) {
          s4[rb][cb] = __builtin_amdgcn_mfma_f32_16x16x32_bf16(
              qfh[rb][ks], kfh[cb], s4[rb][cb], 0, 0, 0);
          s4[rb][cb] = __builtin_amdgcn_mfma_f32_16x16x32_bf16(
              qfh[rb][ks], kfl[cb], s4[rb][cb], 0, 0, 0);
          s4[rb][cb] = __builtin_amdgcn_mfma_f32_16x16x32_bf16(
              qfl[rb][ks], kfh[cb], s4[rb][cb], 0, 0, 0);
        }
    }

    // Online softmax. Row r_glob = rb*16 + g*4 + reg; 16 lanes (lr) share it.
#pragma unroll
    for (int rb = 0; rb < 4; ++rb)
#pragma unroll
      for (int r = 0; r < 4; ++r) {
        float mx = fmaxf(fmaxf(s4[rb][0][r], s4[rb][1][r]),
                         fmaxf(s4[rb][2][r], s4[rb][3][r]));
        mx = fmaxf(mx, __shfl_xor(mx, 1, 16));
        mx = fmaxf(mx, __shfl_xor(mx, 2, 16));
        mx = fmaxf(mx, __shfl_xor(mx, 4, 16));
        mx = fmaxf(mx, __shfl_xor(mx, 8, 16));
        const float mn = fmaxf(m_[rb][r], mx);
        const float fac = __expf(m_[rb][r] - mn);
        m_[rb][r] = mn;
        float sum = 0.f;
#pragma unroll
        for (int cb = 0; cb < 4; ++cb) {
          const float p = __expf(s4[rb][cb][r] - mn);
          s4[rb][cb][r] = p;
          sum += p;
        }
        sum += __shfl_xor(sum, 1, 16);
        sum += __shfl_xor(sum, 2, 16);
        sum += __shfl_xor(sum, 4, 16);
        sum += __shfl_xor(sum, 8, 16);
        l_[rb][r] = l_[rb][r] * fac + sum;
#pragma unroll
        for (int cb = 0; cb < 4; ++cb) o[rb][cb][r] *= fac;
        // P -> per-wave LDS (fp16), same XOR swizzle as K/V tiles
        const int row = rb * 16 + g * 4 + r;
#pragma unroll
        for (int cb = 0; cb < 4; ++cb) {
          const int idx = (row * 64 + cb * 16 + lr) ^ ((row & 7) << 3);
          ((_Float16*)Pw)[idx] = (_Float16)s4[rb][cb][r];
        }
      }

    // O += P @ V (fp16 MFMA). A-frag P: row = rb*16+lr; B-frag V: row=cb*16+lr.
#pragma unroll
    for (int ks = 0; ks < 2; ++ks) {
      f16x8 pf[4], vf[4];
#pragma unroll
      for (int rb = 0; rb < 4; ++rb) {
        const int sl = (rb * 16 + lr) * 8 + ((ks * 4 + g) ^ (lr & 7));
        pf[rb] = *(const f16x8*)(Pw + sl * 8);
      }
#pragma unroll
      for (int cb = 0; cb < 4; ++cb) {
        const int sl = (cb * 16 + lr) * 8 + ((ks * 4 + g) ^ (lr & 7));
        vf[cb] = *(const f16x8*)(VtL + sl * 8);
      }
#pragma unroll
      for (int rb = 0; rb < 4; ++rb)
#pragma unroll
        for (int cb = 0; cb < 4; ++cb)
          o[rb][cb] = __builtin_amdgcn_mfma_f32_16x16x32_f16(
              pf[rb], vf[cb], o[rb][cb], 0, 0, 0);
    }
  }

  // Epilogue: normalize, split hi/lo, write [b, n, h*D + d]
#pragma unroll
  for (int rb = 0; rb < 4; ++rb)
#pragma unroll
    for (int r = 0; r < 4; ++r) {
      const float inv = 1.f / l_[rb][r];
      const int n = q0 + rb * 16 + g * 4 + r;
      const size_t base = ((size_t)bb * N + n) * E + hh * D;
#pragma unroll
      for (int cb = 0; cb < 4; ++cb) {
        ushort hi, lo;
        split2(o[rb][cb][r] * inv, hi, lo);
        Aoh[base + cb * 16 + lr] = hi;
        Aol[base + cb * 16 + lr] = lo;
      }
    }
}

}  // namespace

extern "C" void kernel_launch(void* const* d_in, const int* in_sizes, int n_in,
                              void* d_out, int out_size, void* d_ws,
                              size_t ws_size, hipStream_t stream) {
  (void)in_sizes; (void)n_in; (void)out_size; (void)ws_size;
  const float* x      = (const float*)d_in[0];
  const float* w_qkv  = (const float*)d_in[1];
  const float* b_qkv  = (const float*)d_in[2];
  const float* w_proj = (const float*)d_in[3];
  const float* b_proj = (const float*)d_in[4];
  float* out = (float*)d_out;

  constexpr size_t MB = 1ull << 20;
  char* w = (char*)d_ws;
  ushort* xh  = (ushort*)(w + 0 * MB);    // 16 MB
  ushort* xl  = (ushort*)(w + 16 * MB);   // 16 MB
  ushort* wqh = (ushort*)(w + 32 * MB);   // 6 MB
  ushort* wql = (ushort*)(w + 38 * MB);   // 6 MB
  ushort* wph = (ushort*)(w + 44 * MB);   // 2 MB
  ushort* wpl = (ushort*)(w + 46 * MB);   // 2 MB
  ushort* Aoh = (ushort*)(w + 48 * MB);   // 16 MB
  ushort* Aol = (ushort*)(w + 64 * MB);   // 16 MB
  ushort* Qh  = (ushort*)(w + 80 * MB);   // 16 MB
  ushort* Ql  = (ushort*)(w + 96 * MB);   // 16 MB
  ushort* Kh  = (ushort*)(w + 112 * MB);  // 16 MB
  ushort* Kl  = (ushort*)(w + 128 * MB);  // 16 MB
  ushort* Vt  = (ushort*)(w + 144 * MB);  // 16 MB (fp16)  -> total 160 MB

  split_kernel<<<2048, 256, 0, stream>>>(x, xh, xl, (M * E) / 4);
  split_kernel<<<1024, 256, 0, stream>>>(w_qkv, wqh, wql, (3 * E * E) / 4);
  split_kernel<<<512, 256, 0, stream>>>(w_proj, wph, wpl, (E * E) / 4);

  gemm_x3<0><<<dim3(M / 128, 3 * E / 128), 256, 0, stream>>>(
      xh, xl, wqh, wql, b_qkv, Qh, Ql, Kh, Kl, Vt, nullptr);

  attn_mfma<<<dim3(B * H, N / 256), 256, 0, stream>>>(Qh, Ql, Kh, Kl, Vt, Aoh,
                                                      Aol);

  gemm_x3<1><<<dim3(M / 128, E / 128), 256, 0, stream>>>(
      Aoh, Aol, wph, wpl, b_proj, nullptr, nullptr, nullptr, nullptr, nullptr,
      out);
}